// Round 2
// baseline (1209.260 us; speedup 1.0000x reference)
//
#include <hip/hip_runtime.h>

// ESN reservoir, B=256, T=4096, D=8, U=64, leaky=1.0.
// Single fused kernel: one wave per sequence; lane u owns state[u].
//   - Input projection (x @ W_in + b) * C is computed IN-KERNEL in the
//     prefetch region (8 FMAs/step/lane, hidden under the serial chain's
//     latency). Removes the old Phase-A kernel: no 268 MB x_proj write,
//     no 134 MB refetch.
//   - C = 2*log2(e) so the chain computes tanh(x) = 1 - 2/(exp2(Cx)+1)
//     with no extra multiply on the serial path.
//   - Sparse W_rec column (nnz ~Binomial(64,1/64), capped 12) held as
//     register (byte-lane, C*weight) pairs; cross-lane pull via ds_bpermute.
//   - ALL bpermutes for a step are issued before any dependent FMA so
//     their LDS-crossbar latencies overlap (the old code serialized two
//     rounds behind the Mu>4 branch). The nnz variant is chosen ONCE via
//     template dispatch -> branch-free inner loop.
//   - Input loads are per-lane VMEM (vmcnt) so the bpermute lgkmcnt waits
//     never drain the prefetch (SMEM/DS share lgkmcnt).

constexpr int T_LEN = 4096;
constexpr int B_N   = 256;
constexpr int D_IN  = 8;
constexpr int U_N   = 64;
constexpr int MAXN  = 12;           // max nnz per W_rec column supported
constexpr int GS    = 8;            // timesteps per group (prefetch granule)
constexpr int NG    = T_LEN / GS;   // 512
constexpr float CSC = 2.885390081777927f;  // 2*log2(e)

// Project one timestep: v = C*(x . w + b). w[] and bu are pre-scaled by C.
__device__ __forceinline__ float project8(const float* __restrict__ x,
                                          const float (&w)[D_IN], float bu) {
    const float4* ip = (const float4*)x;
    float4 a = ip[0], c = ip[1];
    float v = bu;
    v = fmaf(a.x, w[0], v); v = fmaf(a.y, w[1], v);
    v = fmaf(a.z, w[2], v); v = fmaf(a.w, w[3], v);
    v = fmaf(c.x, w[4], v); v = fmaf(c.y, w[5], v);
    v = fmaf(c.z, w[6], v); v = fmaf(c.w, w[7], v);
    return v;
}

template<int NS>
__device__ __forceinline__ void run_scan(const float* __restrict__ xin,
                                         float* __restrict__ p,
                                         const float (&w)[D_IN], float bu,
                                         const int (&rsb)[MAXN],
                                         const float (&rw)[MAXN]) {
    static_assert(NS >= 4 && (NS % 2) == 0, "NS even, >=4");
    float state = 0.f;
    float xc[GS], xn[GS];

    // prologue: project group 0 (loads are per-lane VMEM, broadcast-cached)
#pragma unroll
    for (int s = 0; s < GS; ++s) xc[s] = project8(xin + s * D_IN, w, bu);

    for (int g = 0; g < NG; ++g) {
        // prefetch + project next group (clamped tail; redundant is harmless)
        const float* src = xin + (size_t)((g + 1 < NG) ? g + 1 : g) * (GS * D_IN);
#pragma unroll
        for (int s = 0; s < GS; ++s) xn[s] = project8(src + s * D_IN, w, bu);

        float* ps = p + (size_t)g * (GS * U_N);
#pragma unroll
        for (int s = 0; s < GS; ++s) {
            float acc = xc[s];
            const int st = __float_as_int(state);
            // issue ALL cross-lane pulls back-to-back: one LDS latency total
            float t[NS];
#pragma unroll
            for (int j = 0; j < NS; ++j)
                t[j] = __int_as_float(__builtin_amdgcn_ds_bpermute(rsb[j], st));
            // two parallel FMA chains, one join
            float A  = fmaf(rw[0], t[0], acc);
            float Bv = rw[1] * t[1];
#pragma unroll
            for (int j = 2; j + 1 < NS; j += 2) {
                A  = fmaf(rw[j],     t[j],     A);
                Bv = fmaf(rw[j + 1], t[j + 1], Bv);
            }
            acc = A + Bv;
            // acc is already C*x; tanh(x) = 1 - 2/(exp2(C*x)+1)
            float e  = __builtin_amdgcn_exp2f(acc);
            float r  = __builtin_amdgcn_rcpf(e + 1.f);
            float th = fmaf(-2.f, r, 1.f);
            state = th;
            ps[s * U_N] = th;   // coalesced fire-and-forget store (vmcnt)
        }
#pragma unroll
        for (int s = 0; s < GS; ++s) xc[s] = xn[s];
    }
}

__global__ __launch_bounds__(64, 1)
void esn_scan_fused(const float* __restrict__ inputs,  // [B,T,D]
                    const float* __restrict__ W_in,    // [D,U]
                    const float* __restrict__ bias,    // [U]
                    const float* __restrict__ W_rec,   // [U,U]
                    float* __restrict__ out)           // [B,T,U]
{
    const int b = blockIdx.x;
    const int u = threadIdx.x;

    // per-lane input-projection column, pre-scaled by C
    float w[D_IN];
#pragma unroll
    for (int d = 0; d < D_IN; ++d) w[d] = W_in[d * U_N + u] * CSC;
    const float bu = bias[u] * CSC;

    // compress column u of W_rec; pad with zero weights (pull lane 0)
    int rsb[MAXN]; float rw[MAXN];
#pragma unroll
    for (int j = 0; j < MAXN; ++j) { rsb[j] = 0; rw[j] = 0.f; }
    int n = 0;
    for (int k = 0; k < U_N; ++k) {
        float wv = W_rec[k * U_N + u];
        if (wv != 0.f && n < MAXN) { rsb[n] = k << 2; rw[n] = wv * CSC; ++n; }
    }
    // wave-max nnz -> pick variant ONCE (branch-free inner loop)
    int M = n;
#pragma unroll
    for (int off = 32; off > 0; off >>= 1) {
        int o = __shfl_xor(M, off, 64);
        M = (o > M) ? o : M;
    }
    const int Mu = __builtin_amdgcn_readfirstlane(M);

    const float* xin = inputs + (size_t)b * (T_LEN * D_IN);
    float* p = out + (size_t)b * ((size_t)T_LEN * U_N) + u;

    if      (Mu <= 4)  run_scan<4 >(xin, p, w, bu, rsb, rw);
    else if (Mu <= 8)  run_scan<8 >(xin, p, w, bu, rsb, rw);
    else               run_scan<12>(xin, p, w, bu, rsb, rw);
}

extern "C" void kernel_launch(void* const* d_in, const int* in_sizes, int n_in,
                              void* d_out, int out_size, void* d_ws, size_t ws_size,
                              hipStream_t stream) {
    const float* inputs = (const float*)d_in[0];
    const float* W_in   = (const float*)d_in[1];
    const float* bias   = (const float*)d_in[2];
    const float* W_rec  = (const float*)d_in[3];
    float* out = (float*)d_out;

    esn_scan_fused<<<dim3(B_N), dim3(U_N), 0, stream>>>(inputs, W_in, bias, W_rec, out);
}

// Round 3
// 747.400 us; speedup vs baseline: 1.6180x; 1.6180x over previous
//
#include <hip/hip_runtime.h>

// ESN reservoir, B=256, T=4096, D=8, U=64, leaky=1.0.
// Single fused kernel: one wave per sequence; lane u owns state[u].
//
// CRITICAL invariant (round-2 post-mortem): every load issued inside the
// scan loop must be on vmcnt, NEVER lgkmcnt. The projection loads
// (inputs[t]) are wave-uniform, so the compiler scalarizes them to
// s_load (SMEM). SMEM shares lgkmcnt with ds_bpermute, and mixed SMEM+DS
// forces conservative lgkmcnt(0) waits on the serial chain -> the HBM
// prefetch couples into the chain (+255 us, round 2). Fix: add an opaque
// VGPR zero (inline asm) to the index so the address is formally
// divergent -> global_load_dwordx4 on vmcnt, broadcast-coalesced.
//
//   - Input projection (x @ W_in + b) * C computed in-kernel in the
//     prefetch region (8 FMAs/step/lane, off the serial chain). No 268 MB
//     x_proj intermediate.
//   - C = 2*log2(e): tanh(x) = 1 - 2/(exp2(Cx)+1), no multiply on chain.
//   - Sparse W_rec column (nnz ~Binomial(64,1/64), cap 12) as register
//     (byte-lane, C*weight) pairs; cross-lane pull via ds_bpermute.
//   - ALL bpermutes of a step issued back-to-back before any dependent
//     FMA: one LDS-crossbar latency per step, not two. nnz variant chosen
//     once via template dispatch -> branch-free inner loop.

constexpr int T_LEN = 4096;
constexpr int B_N   = 256;
constexpr int D_IN  = 8;
constexpr int U_N   = 64;
constexpr int MAXN  = 12;           // max nnz per W_rec column supported
constexpr int GS    = 8;            // timesteps per group (prefetch granule)
constexpr int NG    = T_LEN / GS;   // 512
constexpr float CSC = 2.885390081777927f;  // 2*log2(e)

// Project one timestep: v = C*(x . w + b). w[] and bu are pre-scaled by C.
// x must be a formally-divergent pointer (see vzero) -> global_load, vmcnt.
__device__ __forceinline__ float project8(const float* __restrict__ x,
                                          const float (&w)[D_IN], float bu) {
    const float4* ip = (const float4*)x;
    float4 a = ip[0], c = ip[1];
    float v = bu;
    v = fmaf(a.x, w[0], v); v = fmaf(a.y, w[1], v);
    v = fmaf(a.z, w[2], v); v = fmaf(a.w, w[3], v);
    v = fmaf(c.x, w[4], v); v = fmaf(c.y, w[5], v);
    v = fmaf(c.z, w[6], v); v = fmaf(c.w, w[7], v);
    return v;
}

template<int NS>
__device__ __forceinline__ void run_scan(const float* __restrict__ xin,
                                         float* __restrict__ p,
                                         const float (&w)[D_IN], float bu,
                                         const int (&rsb)[MAXN],
                                         const float (&rw)[MAXN],
                                         int vzero) {
    static_assert(NS >= 4 && (NS % 2) == 0, "NS even, >=4");
    float state = 0.f;
    float xc[GS], xn[GS];

    // prologue: project group 0. vzero keeps the address divergent (vmcnt).
#pragma unroll
    for (int s = 0; s < GS; ++s)
        xc[s] = project8(xin + s * D_IN + vzero, w, bu);

    for (int g = 0; g < NG; ++g) {
        // prefetch + project next group (clamped tail; redundant is harmless)
        const float* src = xin + (size_t)((g + 1 < NG) ? g + 1 : g) * (GS * D_IN)
                         + vzero;
#pragma unroll
        for (int s = 0; s < GS; ++s) xn[s] = project8(src + s * D_IN, w, bu);

        float* ps = p + (size_t)g * (GS * U_N);
#pragma unroll
        for (int s = 0; s < GS; ++s) {
            float acc = xc[s];
            const int st = __float_as_int(state);
            // issue ALL cross-lane pulls back-to-back: one LDS latency total
            float t[NS];
#pragma unroll
            for (int j = 0; j < NS; ++j)
                t[j] = __int_as_float(__builtin_amdgcn_ds_bpermute(rsb[j], st));
            // two parallel FMA chains, one join
            float A  = fmaf(rw[0], t[0], acc);
            float Bv = rw[1] * t[1];
#pragma unroll
            for (int j = 2; j + 1 < NS; j += 2) {
                A  = fmaf(rw[j],     t[j],     A);
                Bv = fmaf(rw[j + 1], t[j + 1], Bv);
            }
            acc = A + Bv;
            // acc is already C*x; tanh(x) = 1 - 2/(exp2(C*x)+1)
            float e  = __builtin_amdgcn_exp2f(acc);
            float r  = __builtin_amdgcn_rcpf(e + 1.f);
            float th = fmaf(-2.f, r, 1.f);
            state = th;
            ps[s * U_N] = th;   // coalesced fire-and-forget store (vmcnt)
        }
#pragma unroll
        for (int s = 0; s < GS; ++s) xc[s] = xn[s];
    }
}

__global__ __launch_bounds__(64, 1)
void esn_scan_fused(const float* __restrict__ inputs,  // [B,T,D]
                    const float* __restrict__ W_in,    // [D,U]
                    const float* __restrict__ bias,    // [U]
                    const float* __restrict__ W_rec,   // [U,U]
                    float* __restrict__ out)           // [B,T,U]
{
    const int b = blockIdx.x;
    const int u = threadIdx.x;

    // opaque zero in a VGPR: defeats uniform-address scalarization (SMEM)
    // for the in-loop projection loads. See header comment.
    int vzero;
    asm volatile("v_mov_b32 %0, 0" : "=v"(vzero));

    // per-lane input-projection column, pre-scaled by C
    float w[D_IN];
#pragma unroll
    for (int d = 0; d < D_IN; ++d) w[d] = W_in[d * U_N + u] * CSC;
    const float bu = bias[u] * CSC;

    // compress column u of W_rec; pad with zero weights (pull lane 0)
    int rsb[MAXN]; float rw[MAXN];
#pragma unroll
    for (int j = 0; j < MAXN; ++j) { rsb[j] = 0; rw[j] = 0.f; }
    int n = 0;
    for (int k = 0; k < U_N; ++k) {
        float wv = W_rec[k * U_N + u];
        if (wv != 0.f && n < MAXN) { rsb[n] = k << 2; rw[n] = wv * CSC; ++n; }
    }
    // wave-max nnz -> pick variant ONCE (branch-free inner loop)
    int M = n;
#pragma unroll
    for (int off = 32; off > 0; off >>= 1) {
        int o = __shfl_xor(M, off, 64);
        M = (o > M) ? o : M;
    }
    const int Mu = __builtin_amdgcn_readfirstlane(M);

    const float* xin = inputs + (size_t)b * (T_LEN * D_IN);
    float* p = out + (size_t)b * ((size_t)T_LEN * U_N) + u;

    if      (Mu <= 4)  run_scan<4 >(xin, p, w, bu, rsb, rw, vzero);
    else if (Mu <= 8)  run_scan<8 >(xin, p, w, bu, rsb, rw, vzero);
    else               run_scan<12>(xin, p, w, bu, rsb, rw, vzero);
}

extern "C" void kernel_launch(void* const* d_in, const int* in_sizes, int n_in,
                              void* d_out, int out_size, void* d_ws, size_t ws_size,
                              hipStream_t stream) {
    const float* inputs = (const float*)d_in[0];
    const float* W_in   = (const float*)d_in[1];
    const float* bias   = (const float*)d_in[2];
    const float* W_rec  = (const float*)d_in[3];
    float* out = (float*)d_out;

    esn_scan_fused<<<dim3(B_N), dim3(U_N), 0, stream>>>(inputs, W_in, bias, W_rec, out);
}

// Round 4
// 671.186 us; speedup vs baseline: 1.8017x; 1.1136x over previous
//
#include <hip/hip_runtime.h>

// ESN reservoir, B=256, T=4096, D=8, U=64, leaky=1.0.
// Single fused kernel: one wave per sequence; lane u owns state[u].
//
// INVARIANT 1 (round-2): every in-loop load must be on vmcnt, never
// lgkmcnt. Wave-uniform projection loads scalarize to s_load (SMEM),
// which shares lgkmcnt with ds_bpermute -> conservative lgkmcnt(0)
// couples the HBM prefetch into the serial chain (+255 us). Fix: opaque
// VGPR zero (inline asm) added to the index -> global_load, vmcnt.
//
// INVARIANT 2 (round-4): this kernel runs ONE wave per CU -> the static
// schedule IS the wall time. All off-chain work (the next-group input
// projection: 2 loads + 8 FMAs per step) must sit TEXTUALLY between the
// bpermute issues and their first use, so it issues inside the ~120 cy
// DS-crossbar latency shadow instead of serially before the step bodies.
//
//   - Input projection (x @ W_in + b) * C computed in-kernel, one
//     timestep per step body, in the bpermute shadow.
//   - C = 2*log2(e): tanh(x) = 1 - 2/(exp2(Cx)+1), no multiply on chain.
//   - Sparse W_rec column (nnz ~Binomial(64,1/64), cap 12) as register
//     (byte-lane, C*weight) pairs; cross-lane pull via ds_bpermute.
//   - ALL bpermutes of a step issued back-to-back before any dependent
//     FMA: one LDS latency per step. nnz variant chosen once via
//     template dispatch (wave-max) -> branch-free inner loop.

constexpr int T_LEN = 4096;
constexpr int B_N   = 256;
constexpr int D_IN  = 8;
constexpr int U_N   = 64;
constexpr int MAXN  = 12;           // max nnz per W_rec column supported
constexpr int GS    = 8;            // timesteps per group (prefetch granule)
constexpr int NG    = T_LEN / GS;   // 512
constexpr float CSC = 2.885390081777927f;  // 2*log2(e)

// Project one timestep: v = C*(x . w + b). w[] and bu are pre-scaled by C.
// x must be a formally-divergent pointer (see vzero) -> global_load, vmcnt.
__device__ __forceinline__ float project8(const float* __restrict__ x,
                                          const float (&w)[D_IN], float bu) {
    const float4* ip = (const float4*)x;
    float4 a = ip[0], c = ip[1];
    float v = bu;
    v = fmaf(a.x, w[0], v); v = fmaf(a.y, w[1], v);
    v = fmaf(a.z, w[2], v); v = fmaf(a.w, w[3], v);
    v = fmaf(c.x, w[4], v); v = fmaf(c.y, w[5], v);
    v = fmaf(c.z, w[6], v); v = fmaf(c.w, w[7], v);
    return v;
}

template<int NS>
__device__ __forceinline__ void run_scan(const float* __restrict__ xin,
                                         float* __restrict__ p,
                                         const float (&w)[D_IN], float bu,
                                         const int (&rsb)[MAXN],
                                         const float (&rw)[MAXN],
                                         int vzero) {
    static_assert(NS >= 4 && (NS % 2) == 0, "NS even, >=4");
    float state = 0.f;
    float xc[GS], xn[GS];

    // prologue: project group 0 (divergent addr -> vmcnt)
#pragma unroll
    for (int s = 0; s < GS; ++s)
        xc[s] = project8(xin + s * D_IN + vzero, w, bu);

    for (int g = 0; g < NG; ++g) {
        // next-group source (clamped tail; redundant reload is harmless)
        const float* src = xin + (size_t)((g + 1 < NG) ? g + 1 : g) * (GS * D_IN)
                         + vzero;
        float* ps = p + (size_t)g * (GS * U_N);
#pragma unroll
        for (int s = 0; s < GS; ++s) {
            const int st = __float_as_int(state);
            // issue ALL cross-lane pulls back-to-back: one LDS latency total
            float t[NS];
#pragma unroll
            for (int j = 0; j < NS; ++j)
                t[j] = __int_as_float(__builtin_amdgcn_ds_bpermute(rsb[j], st));

            // ---- DS-latency shadow: one timestep of next-group projection
            // (2 global loads + 8 FMAs, independent of t[]) ----
            xn[s] = project8(src + s * D_IN, w, bu);

            // ---- chain: two parallel FMA chains, one join ----
            float A  = fmaf(rw[0], t[0], xc[s]);
            float Bv = rw[1] * t[1];
#pragma unroll
            for (int j = 2; j + 1 < NS; j += 2) {
                A  = fmaf(rw[j],     t[j],     A);
                Bv = fmaf(rw[j + 1], t[j + 1], Bv);
            }
            float acc = A + Bv;
            // acc is already C*x; tanh(x) = 1 - 2/(exp2(C*x)+1)
            float e  = __builtin_amdgcn_exp2f(acc);
            float r  = __builtin_amdgcn_rcpf(e + 1.f);
            float th = fmaf(-2.f, r, 1.f);
            state = th;
            ps[s * U_N] = th;   // coalesced fire-and-forget store (vmcnt)
        }
#pragma unroll
        for (int s = 0; s < GS; ++s) xc[s] = xn[s];
    }
}

__global__ __launch_bounds__(64, 1)
void esn_scan_fused(const float* __restrict__ inputs,  // [B,T,D]
                    const float* __restrict__ W_in,    // [D,U]
                    const float* __restrict__ bias,    // [U]
                    const float* __restrict__ W_rec,   // [U,U]
                    float* __restrict__ out)           // [B,T,U]
{
    const int b = blockIdx.x;
    const int u = threadIdx.x;

    // opaque zero in a VGPR: defeats uniform-address scalarization (SMEM)
    // for the in-loop projection loads. See INVARIANT 1.
    int vzero;
    asm volatile("v_mov_b32 %0, 0" : "=v"(vzero));

    // per-lane input-projection column, pre-scaled by C
    float w[D_IN];
#pragma unroll
    for (int d = 0; d < D_IN; ++d) w[d] = W_in[d * U_N + u] * CSC;
    const float bu = bias[u] * CSC;

    // compress column u of W_rec; pad with zero weights (pull lane 0)
    int rsb[MAXN]; float rw[MAXN];
#pragma unroll
    for (int j = 0; j < MAXN; ++j) { rsb[j] = 0; rw[j] = 0.f; }
    int n = 0;
    for (int k = 0; k < U_N; ++k) {
        float wv = W_rec[k * U_N + u];
        if (wv != 0.f && n < MAXN) { rsb[n] = k << 2; rw[n] = wv * CSC; ++n; }
    }
    // wave-max nnz -> pick variant ONCE (branch-free inner loop)
    int M = n;
#pragma unroll
    for (int off = 32; off > 0; off >>= 1) {
        int o = __shfl_xor(M, off, 64);
        M = (o > M) ? o : M;
    }
    const int Mu = __builtin_amdgcn_readfirstlane(M);

    const float* xin = inputs + (size_t)b * (T_LEN * D_IN);
    float* p = out + (size_t)b * ((size_t)T_LEN * U_N) + u;

    if      (Mu <= 4)  run_scan<4 >(xin, p, w, bu, rsb, rw, vzero);
    else if (Mu <= 6)  run_scan<6 >(xin, p, w, bu, rsb, rw, vzero);
    else if (Mu <= 8)  run_scan<8 >(xin, p, w, bu, rsb, rw, vzero);
    else if (Mu <= 10) run_scan<10>(xin, p, w, bu, rsb, rw, vzero);
    else               run_scan<12>(xin, p, w, bu, rsb, rw, vzero);
}

extern "C" void kernel_launch(void* const* d_in, const int* in_sizes, int n_in,
                              void* d_out, int out_size, void* d_ws, size_t ws_size,
                              hipStream_t stream) {
    const float* inputs = (const float*)d_in[0];
    const float* W_in   = (const float*)d_in[1];
    const float* bias   = (const float*)d_in[2];
    const float* W_rec  = (const float*)d_in[3];
    float* out = (float*)d_out;

    esn_scan_fused<<<dim3(B_N), dim3(U_N), 0, stream>>>(inputs, W_in, bias, W_rec, out);
}